// Round 4
// baseline (137.967 us; speedup 1.0000x reference)
//
#include <hip/hip_runtime.h>

// Tucker scoring: out[n] = sum_{p,q,r} U[i_n,p] V[j_n,q] W[k_n,r] G[p,q,r]
// P=Q=R=32, N=131072, num_time=5000.
//
// Round 8: eliminate the H global round-trip (20.5MB write + 20.5MB read).
//   - scatter_k: bin samples by k, packed {n,i,j,k} records (CAP=128 + ovf).
//   - tucker_eval_fused: per block (4 k's), Phase C computes the 4 H rows
//     H[k] = G x_r W[k] cooperatively: all 256 threads share ONE pass over
//     G (128KB/block, L2-resident) -> 16KB LDS. Phase D (unchanged from
//     round 7): shfl-staged records, double-buffered U/V gathers, 8 lanes
//     x 8 samples per wave iteration. Record/counts/U/V prologue loads are
//     issued before Phase C compute so gather latency hides under it.
// Pipeline: memset(20KB) -> scatter -> eval   (3 dispatches).
// Round-1 coop lesson: per-WAVE H recompute = 640MB G traffic (bad);
// per-BLOCK cooperative recompute = 160MB L2 traffic (fine).

#define BIN_CAP 128

// ---------------------------------------------------------------------------
// scatter: bin samples by k with packed records {n, i, j, k}.
// ---------------------------------------------------------------------------
__global__ __launch_bounds__(256) void scatter_k(const int* __restrict__ K,
                                                 const int* __restrict__ I,
                                                 const int* __restrict__ J,
                                                 int* __restrict__ counts,
                                                 int4* __restrict__ bins,
                                                 int* __restrict__ ovf_cnt,
                                                 int4* __restrict__ ovf,
                                                 int n) {
    for (int idx = blockIdx.x * blockDim.x + threadIdx.x; idx < n;
         idx += gridDim.x * blockDim.x) {
        int k = K[idx];
        int4 rec = make_int4(idx, I[idx], J[idx], k);
        int pos = atomicAdd(&counts[k], 1);
        if (pos < BIN_CAP) {
            bins[(size_t)k * BIN_CAP + pos] = rec;
        } else {
            int o = atomicAdd(ovf_cnt, 1);
            ovf[o] = rec;
        }
    }
}

// ---------------------------------------------------------------------------
// eval (fused H): block owns k = 4*blockIdx .. +3, one k per wave.
// Phase C: thread tid computes H float4-entry tid (pq = 4*tid..4*tid+3) for
//          all 4 k's: 32 float4 of G (each element of G read once per block)
//          dotted against the 4 W rows. Written to Hs4[kk][tid].
// Phase D: wave w evals k=4b+w from Hs4[w]: shfl-staged bin records,
//          double-buffered U/V, 8 lanes x 8 samples per iteration.
// ---------------------------------------------------------------------------
__global__ __launch_bounds__(256) void tucker_eval_fused(
        const float* __restrict__ U, const float* __restrict__ V,
        const float* __restrict__ W, const float* __restrict__ G,
        const int* __restrict__ counts, const int4* __restrict__ bins,
        float* __restrict__ out, int num_time,
        const int* __restrict__ ovf_cnt, const int4* __restrict__ ovf) {
    __shared__ float4 Hs4[4][256];           // 16 KB: one H row per wave
    const int tid = threadIdx.x;
    const int wave = tid >> 6;
    const int lane = tid & 63;
    const int kb = (int)blockIdx.x * 4;
    const int k = kb + wave;
    const int qq = lane & 7;                 // q-quad
    const int s8 = lane >> 3;                // sample slot within iteration

    // ---- issue Phase-D prologue loads FIRST (latency hides under Phase C) --
    int m = 0;
    if (k < num_time) {
        m = counts[k];
        m = (m < BIN_CAP) ? m : BIN_CAP;
    }
    const int kc_bins = (k < num_time) ? k : (num_time - 1);
    const int4* __restrict__ bbase = bins + (size_t)kc_bins * BIN_CAP;
    int4 myrec = bbase[lane];                // lane l holds bin record l

    // ---------------- Phase C: H rows into LDS ----------------
    {
        float acc[4][4];
#pragma unroll
        for (int kk = 0; kk < 4; ++kk)
#pragma unroll
            for (int i = 0; i < 4; ++i) acc[kk][i] = 0.f;

        const float4* __restrict__ G4 = (const float4*)G;
#pragma unroll
        for (int r4 = 0; r4 < 8; ++r4) {
            float4 g[4];
#pragma unroll
            for (int i = 0; i < 4; ++i)
                g[i] = G4[(size_t)(4 * tid + i) * 8 + r4];
#pragma unroll
            for (int kk = 0; kk < 4; ++kk) {
                int kc = kb + kk;
                kc = (kc < num_time) ? kc : (num_time - 1);
                float4 w = ((const float4*)(W + (size_t)kc * 32))[r4];
#pragma unroll
                for (int i = 0; i < 4; ++i)
                    acc[kk][i] += g[i].x * w.x + g[i].y * w.y +
                                  g[i].z * w.z + g[i].w * w.w;
            }
        }
#pragma unroll
        for (int kk = 0; kk < 4; ++kk)
            Hs4[kk][tid] = make_float4(acc[kk][0], acc[kk][1],
                                       acc[kk][2], acc[kk][3]);
    }

    // ---- Phase-D prologue: iteration-0 operands (before the barrier so the
    //      U/V gathers overlap other waves' Phase C + the barrier itself) ----
    float4 u0[8];
    float4 v0 = make_float4(0.f, 0.f, 0.f, 0.f);
    int outn = 0;
    const bool active = (k < num_time) && (m > 0);
    if (active) {
        int src0 = (s8 < m) ? s8 : (m - 1);
        outn   = __shfl(myrec.x, src0, 64);
        int ri = __shfl(myrec.y, src0, 64);
        int rj = __shfl(myrec.z, src0, 64);
        const float4* __restrict__ Ur = (const float4*)(U + (size_t)ri * 32);
#pragma unroll
        for (int p4 = 0; p4 < 8; ++p4) u0[p4] = Ur[p4];
        v0 = ((const float4*)(V + (size_t)rj * 32))[qq];
    }

    __syncthreads();

    // ---------------- Phase D: eval from LDS ----------------
    const float4* __restrict__ Hw = Hs4[wave];
    if (active) {
        const int iters = (m + 7) >> 3;

        for (int t = 0; t < iters; ++t) {
            // ---- issue next iteration's gathers first (hide latency) ----
            float4 u1[8];
            float4 v1;
            int outn_n = 0;
            const int tn = t + 1;
            if (tn < iters) {                 // wave-uniform branch
                int sn = tn * 8 + s8;
                if (sn >= m) sn = m - 1;
                int ni, nj;
                if (sn < 64) {                // uniform per iteration
                    outn_n = __shfl(myrec.x, sn, 64);
                    ni = __shfl(myrec.y, sn, 64);
                    nj = __shfl(myrec.z, sn, 64);
                } else {                      // m > 64: direct load (rare)
                    int4 r = bbase[sn];
                    outn_n = r.x; ni = r.y; nj = r.z;
                }
                const float4* __restrict__ Urn = (const float4*)(U + (size_t)ni * 32);
#pragma unroll
                for (int p4 = 0; p4 < 8; ++p4) u1[p4] = Urn[p4];
                v1 = ((const float4*)(V + (size_t)nj * 32))[qq];
            }

            // ---- compute current iteration from u0/v0 + LDS H ----
            float4 acc = make_float4(0.f, 0.f, 0.f, 0.f);
#pragma unroll
            for (int p4 = 0; p4 < 8; ++p4) {
                float4 h;
                h = Hw[(p4 * 4 + 0) * 8 + qq];
                acc.x += u0[p4].x * h.x; acc.y += u0[p4].x * h.y;
                acc.z += u0[p4].x * h.z; acc.w += u0[p4].x * h.w;
                h = Hw[(p4 * 4 + 1) * 8 + qq];
                acc.x += u0[p4].y * h.x; acc.y += u0[p4].y * h.y;
                acc.z += u0[p4].y * h.z; acc.w += u0[p4].y * h.w;
                h = Hw[(p4 * 4 + 2) * 8 + qq];
                acc.x += u0[p4].z * h.x; acc.y += u0[p4].z * h.y;
                acc.z += u0[p4].z * h.z; acc.w += u0[p4].z * h.w;
                h = Hw[(p4 * 4 + 3) * 8 + qq];
                acc.x += u0[p4].w * h.x; acc.y += u0[p4].w * h.y;
                acc.z += u0[p4].w * h.z; acc.w += u0[p4].w * h.w;
            }
            float sd = acc.x * v0.x + acc.y * v0.y + acc.z * v0.z + acc.w * v0.w;
            sd += __shfl_xor(sd, 1, 64);
            sd += __shfl_xor(sd, 2, 64);
            sd += __shfl_xor(sd, 4, 64);
            const int s = t * 8 + s8;        // real (unclamped) index
            if (s < m && qq == 0) out[outn] = sd;

            // ---- rotate buffers ----
            if (tn < iters) {
#pragma unroll
                for (int p4 = 0; p4 < 8; ++p4) u0[p4] = u1[p4];
                v0 = v1;
                outn = outn_n;
            }
        }
    }

    // --------- overflow drain (rare/never): wave owning k handles it ---------
    if (k < num_time) {
        const int cnt = *ovf_cnt;
        if (cnt > 0) {
            const int pg = lane >> 3;
            for (int s = 0; s < cnt; ++s) {
                int4 rec = ovf[s];
                if (rec.w != k) continue;              // wave-uniform test
                const float* __restrict__ Ur2 = U + (size_t)rec.y * 32;
                float4 acc = make_float4(0.f, 0.f, 0.f, 0.f);
#pragma unroll
                for (int it = 0; it < 4; ++it) {
                    float4 h = Hw[lane + it * 64];
                    float up = Ur2[pg + it * 8];
                    acc.x += up * h.x; acc.y += up * h.y;
                    acc.z += up * h.z; acc.w += up * h.w;
                }
#pragma unroll
                for (int off = 8; off < 64; off <<= 1) {
                    acc.x += __shfl_xor(acc.x, off, 64);
                    acc.y += __shfl_xor(acc.y, off, 64);
                    acc.z += __shfl_xor(acc.z, off, 64);
                    acc.w += __shfl_xor(acc.w, off, 64);
                }
                float4 v4 = ((const float4*)(V + (size_t)rec.z * 32))[qq];
                float sd = acc.x * v4.x + acc.y * v4.y +
                           acc.z * v4.z + acc.w * v4.w;
                sd += __shfl_xor(sd, 1, 64);
                sd += __shfl_xor(sd, 2, 64);
                sd += __shfl_xor(sd, 4, 64);
                if (lane == 0) out[rec.x] = sd;
            }
        }
    }
}

// ---------------------------------------------------------------------------
// Fallbacks for small workspace (H via global memory)
// ---------------------------------------------------------------------------
__global__ __launch_bounds__(256) void build_H(const float* __restrict__ G,
                                               const float* __restrict__ W,
                                               float* __restrict__ H,
                                               int num_time) {
    const int pq4 = threadIdx.x;
    const int kbase = blockIdx.x * 8;

    float acc[8][4];
#pragma unroll
    for (int kk = 0; kk < 8; ++kk)
#pragma unroll
        for (int i = 0; i < 4; ++i) acc[kk][i] = 0.f;

#pragma unroll
    for (int r4 = 0; r4 < 8; ++r4) {
        float4 g[4];
#pragma unroll
        for (int i = 0; i < 4; ++i)
            g[i] = *(const float4*)(G + (size_t)(pq4 * 4 + i) * 32 + r4 * 4);
#pragma unroll
        for (int kk = 0; kk < 8; ++kk) {
            int k = kbase + kk;
            int kc = (k < num_time) ? k : (num_time - 1);
            float4 w = *(const float4*)(W + (size_t)kc * 32 + r4 * 4);
#pragma unroll
            for (int i = 0; i < 4; ++i)
                acc[kk][i] += g[i].x * w.x + g[i].y * w.y + g[i].z * w.z + g[i].w * w.w;
        }
    }

#pragma unroll
    for (int kk = 0; kk < 8; ++kk) {
        int k = kbase + kk;
        if (k < num_time) {
            float4 o = make_float4(acc[kk][0], acc[kk][1], acc[kk][2], acc[kk][3]);
            *(float4*)(H + (size_t)k * 1024 + pq4 * 4) = o;
        }
    }
}

__global__ __launch_bounds__(256) void tucker_eval(const int* __restrict__ I,
                                                   const int* __restrict__ J,
                                                   const int* __restrict__ K,
                                                   const float* __restrict__ U,
                                                   const float* __restrict__ V,
                                                   const float* __restrict__ H,
                                                   float* __restrict__ out,
                                                   int n_samples) {
    const int wave = (int)((blockIdx.x * (unsigned)blockDim.x + threadIdx.x) >> 6);
    const int lane = threadIdx.x & 63;
    if (wave >= n_samples) return;
    const int i = I[wave];
    const int j = J[wave];
    const int k = K[wave];
    const int qq = lane & 7;
    const int pg = lane >> 3;
    const float4* __restrict__ Hrow = (const float4*)(H + (size_t)k * 1024);
    const float* __restrict__ Urow = U + (size_t)i * 32;
    float4 acc = make_float4(0.f, 0.f, 0.f, 0.f);
#pragma unroll
    for (int it = 0; it < 4; ++it) {
        float4 h = Hrow[lane + it * 64];
        float up = Urow[pg + it * 8];
        acc.x += up * h.x; acc.y += up * h.y;
        acc.z += up * h.z; acc.w += up * h.w;
    }
#pragma unroll
    for (int off = 8; off < 64; off <<= 1) {
        acc.x += __shfl_xor(acc.x, off, 64);
        acc.y += __shfl_xor(acc.y, off, 64);
        acc.z += __shfl_xor(acc.z, off, 64);
        acc.w += __shfl_xor(acc.w, off, 64);
    }
    float4 v4 = ((const float4*)(V + (size_t)j * 32))[qq];
    float s = acc.x * v4.x + acc.y * v4.y + acc.z * v4.z + acc.w * v4.w;
    s += __shfl_xor(s, 1, 64);
    s += __shfl_xor(s, 2, 64);
    s += __shfl_xor(s, 4, 64);
    if (lane == 0) out[wave] = s;
}

__global__ __launch_bounds__(256) void tucker_direct(const int* __restrict__ I,
                                                     const int* __restrict__ J,
                                                     const int* __restrict__ K,
                                                     const float* __restrict__ U,
                                                     const float* __restrict__ V,
                                                     const float* __restrict__ W,
                                                     const float* __restrict__ G,
                                                     float* __restrict__ out,
                                                     int n_samples) {
    __shared__ float Gc[4 * 32 * 32];
    const int n = blockIdx.x * blockDim.x + threadIdx.x;
    const bool active = (n < n_samples);
    int i = 0, j = 0, k = 0;
    if (active) { i = I[n]; j = J[n]; k = K[n]; }
    float4 w4[8];
#pragma unroll
    for (int r4 = 0; r4 < 8; ++r4)
        w4[r4] = ((const float4*)(W + (size_t)k * 32))[r4];
    float v[32];
#pragma unroll
    for (int q4 = 0; q4 < 8; ++q4) {
        float4 t = ((const float4*)(V + (size_t)j * 32))[q4];
        v[q4 * 4 + 0] = t.x; v[q4 * 4 + 1] = t.y;
        v[q4 * 4 + 2] = t.z; v[q4 * 4 + 3] = t.w;
    }
    const float* __restrict__ Urow = U + (size_t)i * 32;
    float acc = 0.f;
    for (int c = 0; c < 8; ++c) {
        __syncthreads();
#pragma unroll
        for (int t = 0; t < 4; ++t) {
            int idx = threadIdx.x + t * 256;
            ((float4*)Gc)[idx] = ((const float4*)(G + (size_t)c * 4096))[idx];
        }
        __syncthreads();
        for (int pp = 0; pp < 4; ++pp) {
            float up = Urow[c * 4 + pp];
#pragma unroll
            for (int q = 0; q < 32; ++q) {
                float t0 = 0.f;
#pragma unroll
                for (int r4 = 0; r4 < 8; ++r4) {
                    float4 g = ((const float4*)Gc)[pp * 256 + q * 8 + r4];
                    t0 += g.x * w4[r4].x + g.y * w4[r4].y + g.z * w4[r4].z + g.w * w4[r4].w;
                }
                acc += up * v[q] * t0;
            }
        }
    }
    if (active) out[n] = acc;
}

extern "C" void kernel_launch(void* const* d_in, const int* in_sizes, int n_in,
                              void* d_out, int out_size, void* d_ws, size_t ws_size,
                              hipStream_t stream) {
    const int*   I = (const int*)d_in[0];
    const int*   J = (const int*)d_in[1];
    const int*   K = (const int*)d_in[2];
    const float* U = (const float*)d_in[3];   // [NUM_USER, 32]
    const float* V = (const float*)d_in[4];   // [NUM_ITEM, 32]
    const float* W = (const float*)d_in[5];   // [NUM_TIME, 32]
    const float* G = (const float*)d_in[6];   // [32, 32, 32]
    float* out = (float*)d_out;

    const int n_samples = in_sizes[0];
    const int num_time = in_sizes[5] / 32;

    const size_t h_bytes = (size_t)num_time * 1024 * sizeof(float);
    const size_t z_bytes = (size_t)(num_time + 1) * sizeof(int);   // counts + ovf_cnt
    const size_t z_pad = (z_bytes + 15) & ~(size_t)15;
    const size_t bins_bytes = (size_t)num_time * BIN_CAP * sizeof(int4);
    const size_t ovf_bytes = (size_t)n_samples * sizeof(int4);
    const size_t need_full = h_bytes + z_pad + bins_bytes + ovf_bytes;

    if (ws_size >= need_full) {
        // H region kept in layout for the fallback path; unused in main path.
        int*   counts  = (int*)((char*)d_ws + h_bytes);      // num_time
        int*   ovf_cnt = counts + num_time;                  // 1
        int4*  bins    = (int4*)((char*)d_ws + h_bytes + z_pad);
        int4*  ovf     = (int4*)((char*)d_ws + h_bytes + z_pad + bins_bytes);

        hipMemsetAsync(counts, 0, z_bytes, stream);
        scatter_k<<<512, 256, 0, stream>>>(K, I, J, counts, bins, ovf_cnt, ovf,
                                           n_samples);
        tucker_eval_fused<<<(num_time + 3) / 4, 256, 0, stream>>>(
            U, V, W, G, counts, bins, out, num_time, ovf_cnt, ovf);
    } else if (ws_size >= h_bytes) {
        float* H = (float*)d_ws;
        build_H<<<(num_time + 7) / 8, 256, 0, stream>>>(G, W, H, num_time);
        const long long total_threads = (long long)n_samples * 64;
        tucker_eval<<<(int)((total_threads + 255) / 256), 256, 0, stream>>>(
            I, J, K, U, V, H, out, n_samples);
    } else {
        tucker_direct<<<(n_samples + 255) / 256, 256, 0, stream>>>(
            I, J, K, U, V, W, G, out, n_samples);
    }
}

// Round 5
// 126.105 us; speedup vs baseline: 1.0941x; 1.0941x over previous
//
#include <hip/hip_runtime.h>

// Tucker scoring: out[n] = sum_{p,q,r} U[i_n,p] V[j_n,q] W[k_n,r] G[p,q,r]
// P=Q=R=32, N=131072, num_time=5000.
//
// Round 9: eval restructured block-per-k for parallelism (round-8 lesson:
// eval is latency-bound, 50us @ 6% HBM / 16% occupancy; H-recompute per
// block cost more than the 41MB H round-trip it saved).
//   - fused_prepare (round-3 proven): build_H blocks (H[k]=G x_r W[k]) +
//     scatter blocks (bin samples by k, packed {n,i,j,k}, CAP=128 + ovf).
//   - tucker_eval_bpk: ONE k per 256-thread block (grid=5000). H[k] staged
//     4KB coalesced -> LDS; bin records staged -> LDS; 32 samples in flight
//     (8-lane group per sample); typical m~26 -> single iteration, no
//     serial chain. Low VGPR -> high residency; 5000 short balanced blocks.
// Pipeline: memset(20KB) -> fused_prepare -> eval   (3 dispatches).

#define BIN_CAP 128

// ---------------------------------------------------------------------------
// build_H block body: H[k][pq] = sum_r G[pq][r] * W[k][r], 8 k per block
// ---------------------------------------------------------------------------
__device__ __forceinline__ void build_H_body(const float* __restrict__ G,
                                             const float* __restrict__ W,
                                             float* __restrict__ H,
                                             int num_time, int bblk) {
    const int pq4 = threadIdx.x;            // owns pq in [4*pq4, 4*pq4+4)
    const int kbase = bblk * 8;

    float acc[8][4];
#pragma unroll
    for (int kk = 0; kk < 8; ++kk)
#pragma unroll
        for (int i = 0; i < 4; ++i) acc[kk][i] = 0.f;

#pragma unroll
    for (int r4 = 0; r4 < 8; ++r4) {
        float4 g[4];
#pragma unroll
        for (int i = 0; i < 4; ++i)
            g[i] = *(const float4*)(G + (size_t)(pq4 * 4 + i) * 32 + r4 * 4);
#pragma unroll
        for (int kk = 0; kk < 8; ++kk) {
            int k = kbase + kk;
            int kc = (k < num_time) ? k : (num_time - 1);
            float4 w = *(const float4*)(W + (size_t)kc * 32 + r4 * 4);
#pragma unroll
            for (int i = 0; i < 4; ++i)
                acc[kk][i] += g[i].x * w.x + g[i].y * w.y + g[i].z * w.z + g[i].w * w.w;
        }
    }

#pragma unroll
    for (int kk = 0; kk < 8; ++kk) {
        int k = kbase + kk;
        if (k < num_time) {
            float4 o = make_float4(acc[kk][0], acc[kk][1], acc[kk][2], acc[kk][3]);
            *(float4*)(H + (size_t)k * 1024 + pq4 * 4) = o;
        }
    }
}

// ---------------------------------------------------------------------------
// scatter block body: bin samples by k with packed records {n, i, j, k}
// ---------------------------------------------------------------------------
__device__ __forceinline__ void scatter_body(const int* __restrict__ K,
                                             const int* __restrict__ I,
                                             const int* __restrict__ J,
                                             int* __restrict__ counts,
                                             int4* __restrict__ bins,
                                             int* __restrict__ ovf_cnt,
                                             int4* __restrict__ ovf,
                                             int n, int sblk, int nsblk) {
    for (int idx = sblk * 256 + (int)threadIdx.x; idx < n; idx += nsblk * 256) {
        int k = K[idx];
        int4 rec = make_int4(idx, I[idx], J[idx], k);
        int pos = atomicAdd(&counts[k], 1);
        if (pos < BIN_CAP) {
            bins[(size_t)k * BIN_CAP + pos] = rec;
        } else {
            int o = atomicAdd(ovf_cnt, 1);
            ovf[o] = rec;
        }
    }
}

// ---------------------------------------------------------------------------
// fused_prepare: blocks [0,nbuild) run build_H, blocks [nbuild,...) scatter.
// ---------------------------------------------------------------------------
__global__ __launch_bounds__(256) void fused_prepare(
        const float* __restrict__ G, const float* __restrict__ W,
        float* __restrict__ H,
        const int* __restrict__ K, const int* __restrict__ I,
        const int* __restrict__ J, int* __restrict__ counts,
        int4* __restrict__ bins, int* __restrict__ ovf_cnt,
        int4* __restrict__ ovf, int n, int num_time,
        int nbuild, int nscatter) {
    const int b = blockIdx.x;
    if (b < nbuild) {
        build_H_body(G, W, H, num_time, b);
    } else {
        scatter_body(K, I, J, counts, bins, ovf_cnt, ovf, n, b - nbuild, nscatter);
    }
}

// Standalone build_H (mid-tier fallback path)
__global__ __launch_bounds__(256) void build_H(const float* __restrict__ G,
                                               const float* __restrict__ W,
                                               float* __restrict__ H,
                                               int num_time) {
    build_H_body(G, W, H, num_time, blockIdx.x);
}

// ---------------------------------------------------------------------------
// eval: block per k (grid = num_time). H[k] 4KB -> LDS (coalesced), bin
// records -> LDS. 32 samples in flight: 8-lane group per sample, group g
// handles sample s0+g. Per lane: acc4 = sum_p u_p * H[p][4qq..4qq+3] from
// conflict-free LDS broadcasts; dot with v4; reduce via shfl_xor 1/2/4.
// Typical m~26 -> one iteration. Overflow drained grid-stride (global H).
// ---------------------------------------------------------------------------
__global__ __launch_bounds__(256) void tucker_eval_bpk(
        const float* __restrict__ U, const float* __restrict__ V,
        const float* __restrict__ H, const int* __restrict__ counts,
        const int4* __restrict__ bins, float* __restrict__ out,
        int num_time, const int* __restrict__ ovf_cnt,
        const int4* __restrict__ ovf) {
    __shared__ float4 Hs[256];               // 4 KB: H row for this k
    __shared__ int4 Rs[BIN_CAP];             // 2 KB: staged records
    const int tid = threadIdx.x;
    const int k = (int)blockIdx.x;
    const int qq = tid & 7;                  // q-quad within sample group
    const int g = tid >> 3;                  // sample group 0..31

    // counts first (predicate for record staging), then bulk loads issue
    int m = counts[k];
    m = (m < BIN_CAP) ? m : BIN_CAP;

    const float4* __restrict__ Hrow = (const float4*)(H + (size_t)k * 1024);
    Hs[tid] = Hrow[tid];                     // 4KB coalesced
    if (tid < m) Rs[tid] = bins[(size_t)k * BIN_CAP + tid];
    __syncthreads();

    for (int s0 = 0; s0 < m; s0 += 32) {
        const int s = s0 + g;                // group-uniform
        if (s < m) {
            int4 rec = Rs[s];
            const float4* __restrict__ Ur = (const float4*)(U + (size_t)rec.y * 32);
            float4 u[8];
#pragma unroll
            for (int p4 = 0; p4 < 8; ++p4) u[p4] = Ur[p4];
            float4 v4 = ((const float4*)(V + (size_t)rec.z * 32))[qq];

            float4 acc = make_float4(0.f, 0.f, 0.f, 0.f);
#pragma unroll
            for (int p4 = 0; p4 < 8; ++p4) {
                float4 h;
                h = Hs[(p4 * 4 + 0) * 8 + qq];
                acc.x += u[p4].x * h.x; acc.y += u[p4].x * h.y;
                acc.z += u[p4].x * h.z; acc.w += u[p4].x * h.w;
                h = Hs[(p4 * 4 + 1) * 8 + qq];
                acc.x += u[p4].y * h.x; acc.y += u[p4].y * h.y;
                acc.z += u[p4].y * h.z; acc.w += u[p4].y * h.w;
                h = Hs[(p4 * 4 + 2) * 8 + qq];
                acc.x += u[p4].z * h.x; acc.y += u[p4].z * h.y;
                acc.z += u[p4].z * h.z; acc.w += u[p4].z * h.w;
                h = Hs[(p4 * 4 + 3) * 8 + qq];
                acc.x += u[p4].w * h.x; acc.y += u[p4].w * h.y;
                acc.z += u[p4].w * h.z; acc.w += u[p4].w * h.w;
            }
            float sd = acc.x * v4.x + acc.y * v4.y + acc.z * v4.z + acc.w * v4.w;
            sd += __shfl_xor(sd, 1, 64);
            sd += __shfl_xor(sd, 2, 64);
            sd += __shfl_xor(sd, 4, 64);
            if (qq == 0) out[rec.x] = sd;
        }
    }

    // --------- overflow drain (rare/never): wave per spill record ---------
    const int cnt = *ovf_cnt;
    if (cnt > 0) {
        const int wave = tid >> 6;
        const int lane = tid & 63;
        const int gwave = k * 4 + wave;
        const int nw = (int)gridDim.x * 4;
        const int pg = lane >> 3;
        const int qq6 = lane & 7;
        for (int s = gwave; s < cnt; s += nw) {
            int4 rec = ovf[s];
            const float4* __restrict__ Hrow2 = (const float4*)(H + (size_t)rec.w * 1024);
            const float* __restrict__ Ur = U + (size_t)rec.y * 32;

            float4 acc = make_float4(0.f, 0.f, 0.f, 0.f);
#pragma unroll
            for (int it = 0; it < 4; ++it) {
                float4 h = Hrow2[lane + it * 64];
                float up = Ur[pg + it * 8];
                acc.x += up * h.x; acc.y += up * h.y;
                acc.z += up * h.z; acc.w += up * h.w;
            }
#pragma unroll
            for (int off = 8; off < 64; off <<= 1) {
                acc.x += __shfl_xor(acc.x, off, 64);
                acc.y += __shfl_xor(acc.y, off, 64);
                acc.z += __shfl_xor(acc.z, off, 64);
                acc.w += __shfl_xor(acc.w, off, 64);
            }
            float4 v4 = ((const float4*)(V + (size_t)rec.z * 32))[qq6];
            float sd = acc.x * v4.x + acc.y * v4.y + acc.z * v4.z + acc.w * v4.w;
            sd += __shfl_xor(sd, 1, 64);
            sd += __shfl_xor(sd, 2, 64);
            sd += __shfl_xor(sd, 4, 64);
            if (lane == 0) out[rec.x] = sd;
        }
    }
}

// ---------------------------------------------------------------------------
// Fallbacks for small workspace
// ---------------------------------------------------------------------------
__global__ __launch_bounds__(256) void tucker_eval(const int* __restrict__ I,
                                                   const int* __restrict__ J,
                                                   const int* __restrict__ K,
                                                   const float* __restrict__ U,
                                                   const float* __restrict__ V,
                                                   const float* __restrict__ H,
                                                   float* __restrict__ out,
                                                   int n_samples) {
    const int wave = (int)((blockIdx.x * (unsigned)blockDim.x + threadIdx.x) >> 6);
    const int lane = threadIdx.x & 63;
    if (wave >= n_samples) return;
    const int i = I[wave];
    const int j = J[wave];
    const int k = K[wave];
    const int qq = lane & 7;
    const int pg = lane >> 3;
    const float4* __restrict__ Hrow = (const float4*)(H + (size_t)k * 1024);
    const float* __restrict__ Urow = U + (size_t)i * 32;
    float4 acc = make_float4(0.f, 0.f, 0.f, 0.f);
#pragma unroll
    for (int it = 0; it < 4; ++it) {
        float4 h = Hrow[lane + it * 64];
        float up = Urow[pg + it * 8];
        acc.x += up * h.x; acc.y += up * h.y;
        acc.z += up * h.z; acc.w += up * h.w;
    }
#pragma unroll
    for (int off = 8; off < 64; off <<= 1) {
        acc.x += __shfl_xor(acc.x, off, 64);
        acc.y += __shfl_xor(acc.y, off, 64);
        acc.z += __shfl_xor(acc.z, off, 64);
        acc.w += __shfl_xor(acc.w, off, 64);
    }
    float4 v4 = ((const float4*)(V + (size_t)j * 32))[qq];
    float s = acc.x * v4.x + acc.y * v4.y + acc.z * v4.z + acc.w * v4.w;
    s += __shfl_xor(s, 1, 64);
    s += __shfl_xor(s, 2, 64);
    s += __shfl_xor(s, 4, 64);
    if (lane == 0) out[wave] = s;
}

__global__ __launch_bounds__(256) void tucker_direct(const int* __restrict__ I,
                                                     const int* __restrict__ J,
                                                     const int* __restrict__ K,
                                                     const float* __restrict__ U,
                                                     const float* __restrict__ V,
                                                     const float* __restrict__ W,
                                                     const float* __restrict__ G,
                                                     float* __restrict__ out,
                                                     int n_samples) {
    __shared__ float Gc[4 * 32 * 32];
    const int n = blockIdx.x * blockDim.x + threadIdx.x;
    const bool active = (n < n_samples);
    int i = 0, j = 0, k = 0;
    if (active) { i = I[n]; j = J[n]; k = K[n]; }
    float4 w4[8];
#pragma unroll
    for (int r4 = 0; r4 < 8; ++r4)
        w4[r4] = ((const float4*)(W + (size_t)k * 32))[r4];
    float v[32];
#pragma unroll
    for (int q4 = 0; q4 < 8; ++q4) {
        float4 t = ((const float4*)(V + (size_t)j * 32))[q4];
        v[q4 * 4 + 0] = t.x; v[q4 * 4 + 1] = t.y;
        v[q4 * 4 + 2] = t.z; v[q4 * 4 + 3] = t.w;
    }
    const float* __restrict__ Urow = U + (size_t)i * 32;
    float acc = 0.f;
    for (int c = 0; c < 8; ++c) {
        __syncthreads();
#pragma unroll
        for (int t = 0; t < 4; ++t) {
            int idx = threadIdx.x + t * 256;
            ((float4*)Gc)[idx] = ((const float4*)(G + (size_t)c * 4096))[idx];
        }
        __syncthreads();
        for (int pp = 0; pp < 4; ++pp) {
            float up = Urow[c * 4 + pp];
#pragma unroll
            for (int q = 0; q < 32; ++q) {
                float t0 = 0.f;
#pragma unroll
                for (int r4 = 0; r4 < 8; ++r4) {
                    float4 g = ((const float4*)Gc)[pp * 256 + q * 8 + r4];
                    t0 += g.x * w4[r4].x + g.y * w4[r4].y + g.z * w4[r4].z + g.w * w4[r4].w;
                }
                acc += up * v[q] * t0;
            }
        }
    }
    if (active) out[n] = acc;
}

extern "C" void kernel_launch(void* const* d_in, const int* in_sizes, int n_in,
                              void* d_out, int out_size, void* d_ws, size_t ws_size,
                              hipStream_t stream) {
    const int*   I = (const int*)d_in[0];
    const int*   J = (const int*)d_in[1];
    const int*   K = (const int*)d_in[2];
    const float* U = (const float*)d_in[3];   // [NUM_USER, 32]
    const float* V = (const float*)d_in[4];   // [NUM_ITEM, 32]
    const float* W = (const float*)d_in[5];   // [NUM_TIME, 32]
    const float* G = (const float*)d_in[6];   // [32, 32, 32]
    float* out = (float*)d_out;

    const int n_samples = in_sizes[0];
    const int num_time = in_sizes[5] / 32;

    const size_t h_bytes = (size_t)num_time * 1024 * sizeof(float);
    const size_t z_bytes = (size_t)(num_time + 1) * sizeof(int);   // counts + ovf_cnt
    const size_t z_pad = (z_bytes + 15) & ~(size_t)15;
    const size_t bins_bytes = (size_t)num_time * BIN_CAP * sizeof(int4);
    const size_t ovf_bytes = (size_t)n_samples * sizeof(int4);
    const size_t need_full = h_bytes + z_pad + bins_bytes + ovf_bytes;

    if (ws_size >= need_full) {
        float* H       = (float*)d_ws;
        int*   counts  = (int*)((char*)d_ws + h_bytes);      // num_time
        int*   ovf_cnt = counts + num_time;                  // 1
        int4*  bins    = (int4*)((char*)d_ws + h_bytes + z_pad);
        int4*  ovf     = (int4*)((char*)d_ws + h_bytes + z_pad + bins_bytes);

        const int nbuild = (num_time + 7) / 8;
        const int nscatter = 512;

        hipMemsetAsync(counts, 0, z_bytes, stream);
        fused_prepare<<<nbuild + nscatter, 256, 0, stream>>>(
            G, W, H, K, I, J, counts, bins, ovf_cnt, ovf,
            n_samples, num_time, nbuild, nscatter);
        tucker_eval_bpk<<<num_time, 256, 0, stream>>>(
            U, V, H, counts, bins, out, num_time, ovf_cnt, ovf);
    } else if (ws_size >= h_bytes) {
        float* H = (float*)d_ws;
        build_H<<<(num_time + 7) / 8, 256, 0, stream>>>(G, W, H, num_time);
        const long long total_threads = (long long)n_samples * 64;
        tucker_eval<<<(int)((total_threads + 255) / 256), 256, 0, stream>>>(
            I, J, K, U, V, H, out, n_samples);
    } else {
        tucker_direct<<<(n_samples + 255) / 256, 256, 0, stream>>>(
            I, J, K, U, V, W, G, out, n_samples);
    }
}